// Round 12
// baseline (141.614 us; speedup 1.0000x reference)
//
#include <hip/hip_runtime.h>
#include <math.h>

#define BB 4096
#define FF 64
#define RR 16   // F / RED
#define DD 512
#define KK 8
#define NV (KK * DD / 4)   // 1024 f32x4 per batch output

typedef float f32x4 __attribute__((ext_vector_type(4)));

// Two batches per block (A = 2*bid, B = 2*bid+1), software-pipelined:
//   stage1(A) | bar | MLP(A)@wave0 ∥ stage1(B)@all | bar | MLP(B)@wave0 ∥
//   gather(A)@waves1-3 | bar | gather(B)@all
// Keeps HBM busy through the MLP tails; 3 barriers per 2 batches (R9 had 8).
// All arithmetic BIT-FROZEN from the passing R8/R9 kernel.
__global__ __launch_bounds__(256) void ca1d_fused(
    const float* __restrict__ x,   // [B,F,D]
    const float* __restrict__ w1,  // [R,F]
    const float* __restrict__ b1,  // [R]
    const float* __restrict__ w2,  // [F,R]
    const float* __restrict__ b2,  // [F]
    float* __restrict__ out)       // [B,K,D]
{
    __shared__ double s_pooled[2][FF];
    __shared__ double s_h[2][RR];
    __shared__ double s_z[2][FF];
    __shared__ float  s_w[2][FF];
    __shared__ int    s_idx[2][KK];

    const int tid  = threadIdx.x;
    const int lane = tid & 63;
    const int wave = tid >> 6;   // 0..3

    const size_t b0 = (size_t)blockIdx.x * 2;
    const float* xA = x + b0 * FF * DD;
    const float* xB = xA + FF * DD;

    // ---- Stage 1 (BIT-FROZEN): pooled[f] = mean; per-lane pair tree,
    // xor-shuffle 32,16,8,4,2,1, *1/512 by lane 0. Wave w owns rows {w,w+4,...}.
    auto stage1 = [&](const float* __restrict__ xb, double* pooled) {
        #pragma unroll 4
        for (int f = wave; f < FF; f += 4) {
            const float4* row = reinterpret_cast<const float4*>(xb + f * DD);
            float4 v0 = row[lane];        // coalesced 1 KiB/instr
            float4 v1 = row[lane + 64];
            double s = ((double)v0.x + (double)v0.y) + ((double)v0.z + (double)v0.w)
                     + ((double)v1.x + (double)v1.y) + ((double)v1.z + (double)v1.w);
            #pragma unroll
            for (int off = 32; off > 0; off >>= 1)
                s += __shfl_xor(s, off, 64);
            if (lane == 0) pooled[f] = s * (1.0 / DD);
        }
    };

    // ---- Stages 2-4 (BIT-FROZEN), wave 0 only. Same-wave LDS ops are
    // architecturally in-order -> no block barriers needed inside.
    auto mlp = [&](int p) {
        // Stage 2: h[r] = relu(dot(pooled, w1[r,:]) + b1[r])  (f64, lanes 0-15)
        if (lane < RR) {
            double acc = (double)b1[lane];
            const float* wr = w1 + lane * FF;
            #pragma unroll
            for (int f = 0; f < FF; ++f) acc += s_pooled[p][f] * (double)wr[f];
            s_h[p][lane] = acc > 0.0 ? acc : 0.0;
        }
        // Stage 3: z[f] = dot(h, w2[f,:]) + b2[f]  (f64, all 64 lanes = old tid<64)
        {
            double acc = (double)b2[lane];
            const float* wf = w2 + lane * RR;
            #pragma unroll
            for (int r = 0; r < RR; ++r) acc += s_h[p][r] * (double)wf[r];
            s_z[p][lane] = acc;
        }
        // Stage 4: three-rounding sigmoid chain + rank selection
        // (descending w, exact ties -> lower index)
        {
            float e   = (float)exp(-s_z[p][lane]);   // f64 exp -> f32 round
            float den = 1.0f + e;                    // f32 round
            float v   = 1.0f / den;                  // f32 round
            s_w[p][lane] = v;
            int rank = 0;
            #pragma unroll
            for (int j = 0; j < FF; ++j) {
                float wj = s_w[p][j];                // uniform broadcast
                rank += (wj > v || (wj == v && j < lane)) ? 1 : 0;
            }
            if (rank < KK) s_idx[p][rank] = lane;
        }
    };

    // ---- Stage 5: gather 8 selected rows -> out[b,k,:], nt stores
    auto gather = [&](int p, const float* __restrict__ xb, int t, int nthreads) {
        f32x4* obv = (f32x4*)(out + (b0 + p) * (size_t)(KK * DD));
        for (int i = t; i < NV; i += nthreads) {
            int k = i >> 7;        // / 128
            int c = i & 127;
            const f32x4* src = (const f32x4*)(xb + (size_t)s_idx[p][k] * DD);
            __builtin_nontemporal_store(src[c], obv + i);
        }
    };

    stage1(xA, s_pooled[0]);
    __syncthreads();                    // bar1: pooled(A) complete

    if (wave == 0) mlp(0);              // MLP(A) on wave 0 ...
    stage1(xB, s_pooled[1]);            // ... while all waves stream B
    __syncthreads();                    // bar2: idx(A) + pooled(B) complete

    if (wave == 0) mlp(1);              // MLP(B) on wave 0 ...
    else gather(0, xA, tid - 64, 192);  // ... while waves 1-3 gather A
    __syncthreads();                    // bar3: idx(B) complete

    gather(1, xB, tid, 256);            // all waves gather B
}

extern "C" void kernel_launch(void* const* d_in, const int* in_sizes, int n_in,
                              void* d_out, int out_size, void* d_ws, size_t ws_size,
                              hipStream_t stream) {
    const float* x  = (const float*)d_in[0];
    const float* w1 = (const float*)d_in[1];
    const float* b1 = (const float*)d_in[2];
    const float* w2 = (const float*)d_in[3];
    const float* b2 = (const float*)d_in[4];
    float* out = (float*)d_out;

    ca1d_fused<<<BB / 2, 256, 0, stream>>>(x, w1, b1, w2, b2, out);
}

// Round 13
// 119.062 us; speedup vs baseline: 1.1894x; 1.1894x over previous
//
#include <hip/hip_runtime.h>
#include <math.h>

#define BB 4096
#define FF 64
#define RR 16   // F / RED
#define DD 512
#define KK 8

typedef float f32x4 __attribute__((ext_vector_type(4)));

// R9 structure (best: 114.6 us) with stages 2-4 merged onto wave 0:
// same lanes, same op order, same LDS cells -> bit-identical; removes 2 of 4
// block barriers. One block per batch, 256 threads, tiny LDS -> 8 blocks/CU.
__global__ __launch_bounds__(256) void ca1d_fused(
    const float* __restrict__ x,   // [B,F,D]
    const float* __restrict__ w1,  // [R,F]
    const float* __restrict__ b1,  // [R]
    const float* __restrict__ w2,  // [F,R]
    const float* __restrict__ b2,  // [F]
    float* __restrict__ out)       // [B,K,D]
{
    __shared__ double s_pooled[FF];
    __shared__ double s_h[RR];
    __shared__ float  s_w[FF];
    __shared__ int    s_idx[KK];

    const int b    = blockIdx.x;
    const int tid  = threadIdx.x;
    const int lane = tid & 63;
    const int wave = tid >> 6;   // 0..3

    const float* xb = x + (size_t)b * FF * DD;

    // ---- Stage 1 (BIT-FROZEN): pooled[f] = mean_D x[b,f,:].
    // Per-lane pair tree, xor-shuffle 32,16,8,4,2,1, *1/512 by lane 0.
    // unroll 4 -> 8 float4 loads + 4 independent shuffle chains in flight.
    #pragma unroll 4
    for (int f = wave; f < FF; f += 4) {
        const float4* row = reinterpret_cast<const float4*>(xb + f * DD);
        float4 v0 = row[lane];        // coalesced: 64 lanes x 16B
        float4 v1 = row[lane + 64];
        double s = ((double)v0.x + (double)v0.y) + ((double)v0.z + (double)v0.w)
                 + ((double)v1.x + (double)v1.y) + ((double)v1.z + (double)v1.w);
        #pragma unroll
        for (int off = 32; off > 0; off >>= 1)
            s += __shfl_xor(s, off, 64);
        if (lane == 0) s_pooled[f] = s * (1.0 / DD);
    }
    __syncthreads();   // pooled complete

    // ---- Stages 2-4 on wave 0 only (same-wave LDS ops are in-order;
    // hardware lgkmcnt orders the s_h/s_w write->read chains). BIT-FROZEN.
    if (wave == 0) {
        // Stage 2: h[r] = relu(dot(pooled, w1[r,:]) + b1[r])  (f64, lanes 0-15)
        if (lane < RR) {
            double acc = (double)b1[lane];
            const float* wr = w1 + lane * FF;
            #pragma unroll
            for (int f = 0; f < FF; ++f) acc += s_pooled[f] * (double)wr[f];
            s_h[lane] = acc > 0.0 ? acc : 0.0;
        }
        // Stage 3: z[f] = dot(h, w2[f,:]) + b2[f]  (f64, all 64 lanes)
        double acc = (double)b2[lane];
        const float* wf = w2 + lane * RR;
        #pragma unroll
        for (int r = 0; r < RR; ++r) acc += s_h[r] * (double)wf[r];
        // Stage 4: three-rounding sigmoid chain + rank selection
        // (descending w, exact ties -> lower index)
        float e   = (float)exp(-acc);    // f64 exp -> f32 round
        float den = 1.0f + e;            // f32 round
        float v   = 1.0f / den;          // f32 round
        s_w[lane] = v;
        int rank = 0;
        #pragma unroll
        for (int j = 0; j < FF; ++j) {
            float wj = s_w[j];           // uniform broadcast, conflict-free
            rank += (wj > v || (wj == v && j < lane)) ? 1 : 0;
        }
        if (rank < KK) s_idx[rank] = lane;
    }
    __syncthreads();   // idx complete

    // ---- Stage 5: gather 8 selected rows -> out[b, k, :], nt stores
    // (out is never re-read; keep L2 for x rows).
    f32x4* ob = (f32x4*)(out + (size_t)b * KK * DD);
    #pragma unroll
    for (int i = tid; i < KK * DD / 4; i += 256) {   // 1024 float4, 4 per thread
        int k = i >> 7;        // / 128
        int c = i & 127;
        const f32x4* src = (const f32x4*)(xb + (size_t)s_idx[k] * DD);
        __builtin_nontemporal_store(src[c], ob + i);
    }
}

extern "C" void kernel_launch(void* const* d_in, const int* in_sizes, int n_in,
                              void* d_out, int out_size, void* d_ws, size_t ws_size,
                              hipStream_t stream) {
    const float* x  = (const float*)d_in[0];
    const float* w1 = (const float*)d_in[1];
    const float* b1 = (const float*)d_in[2];
    const float* w2 = (const float*)d_in[3];
    const float* b2 = (const float*)d_in[4];
    float* out = (float*)d_out;

    ca1d_fused<<<BB, 256, 0, stream>>>(x, w1, b1, w2, b2, out);
}

// Round 14
// 118.957 us; speedup vs baseline: 1.1905x; 1.0009x over previous
//
#include <hip/hip_runtime.h>
#include <math.h>

#define BB 4096
#define FF 64
#define RR 16   // F / RED
#define DD 512
#define KK 8

typedef float f32x4 __attribute__((ext_vector_type(4)));

// ---------------- Kernel A: pool + MLP + top-k -> indices to d_ws ----------
// Pure read-stream (512 MiB) + one barrier; no gather phase at all.
// Arithmetic BIT-FROZEN from the passing R8/R9/R13 kernels.
__global__ __launch_bounds__(256) void ca1d_score(
    const float* __restrict__ x,   // [B,F,D]
    const float* __restrict__ w1,  // [R,F]
    const float* __restrict__ b1,  // [R]
    const float* __restrict__ w2,  // [F,R]
    const float* __restrict__ b2,  // [F]
    int* __restrict__ idx_out)     // [B,K]
{
    __shared__ double s_pooled[FF];
    __shared__ double s_h[RR];
    __shared__ float  s_w[FF];

    const int b    = blockIdx.x;
    const int tid  = threadIdx.x;
    const int lane = tid & 63;
    const int wave = tid >> 6;   // 0..3

    const float* xb = x + (size_t)b * FF * DD;

    // ---- Stage 1 (BIT-FROZEN): pooled[f] = mean_D x[b,f,:].
    // Per-lane pair tree, xor-shuffle 32,16,8,4,2,1, *1/512 by lane 0.
    #pragma unroll 4
    for (int f = wave; f < FF; f += 4) {
        const float4* row = reinterpret_cast<const float4*>(xb + f * DD);
        float4 v0 = row[lane];        // coalesced: 64 lanes x 16B
        float4 v1 = row[lane + 64];
        double s = ((double)v0.x + (double)v0.y) + ((double)v0.z + (double)v0.w)
                 + ((double)v1.x + (double)v1.y) + ((double)v1.z + (double)v1.w);
        #pragma unroll
        for (int off = 32; off > 0; off >>= 1)
            s += __shfl_xor(s, off, 64);
        if (lane == 0) s_pooled[f] = s * (1.0 / DD);
    }
    __syncthreads();   // pooled complete — the ONLY barrier

    // ---- Stages 2-4 on wave 0 (same-wave LDS ordering; BIT-FROZEN).
    if (wave == 0) {
        // Stage 2: h[r] = relu(dot(pooled, w1[r,:]) + b1[r])  (f64, lanes 0-15)
        if (lane < RR) {
            double acc = (double)b1[lane];
            const float* wr = w1 + lane * FF;
            #pragma unroll
            for (int f = 0; f < FF; ++f) acc += s_pooled[f] * (double)wr[f];
            s_h[lane] = acc > 0.0 ? acc : 0.0;
        }
        // Stage 3: z[f] = dot(h, w2[f,:]) + b2[f]  (f64, all 64 lanes)
        double acc = (double)b2[lane];
        const float* wf = w2 + lane * RR;
        #pragma unroll
        for (int r = 0; r < RR; ++r) acc += s_h[r] * (double)wf[r];
        // Stage 4: three-rounding sigmoid chain + rank selection
        // (descending w, exact ties -> lower index)
        float e   = (float)exp(-acc);    // f64 exp -> f32 round
        float den = 1.0f + e;            // f32 round
        float v   = 1.0f / den;          // f32 round
        s_w[lane] = v;
        int rank = 0;
        #pragma unroll
        for (int j = 0; j < FF; ++j) {
            float wj = s_w[j];           // uniform broadcast, conflict-free
            rank += (wj > v || (wj == v && j < lane)) ? 1 : 0;
        }
        if (rank < KK) idx_out[b * KK + rank] = lane;   // straight from registers
    }
}

// ---------------- Kernel B: pure gather-copy ------------------------------
// 64 MiB coalesced read + 64 MiB coalesced nt write; no barriers, no LDS.
__global__ __launch_bounds__(256) void ca1d_gather(
    const float* __restrict__ x,       // [B,F,D]
    const int*   __restrict__ idx_in,  // [B,K]
    float* __restrict__ out)           // [B,K,D]
{
    const int b   = blockIdx.x;
    const int tid = threadIdx.x;

    const float* xb = x + (size_t)b * FF * DD;
    f32x4* ob = (f32x4*)(out + (size_t)b * KK * DD);

    #pragma unroll
    for (int i = tid; i < KK * DD / 4; i += 256) {   // 1024 f32x4, 4 per thread
        int k = i >> 7;        // / 128
        int c = i & 127;
        int f = idx_in[b * KK + k];                  // broadcast load, L2-hot
        const f32x4* src = (const f32x4*)(xb + (size_t)f * DD);
        __builtin_nontemporal_store(src[c], ob + i);
    }
}

extern "C" void kernel_launch(void* const* d_in, const int* in_sizes, int n_in,
                              void* d_out, int out_size, void* d_ws, size_t ws_size,
                              hipStream_t stream) {
    const float* x  = (const float*)d_in[0];
    const float* w1 = (const float*)d_in[1];
    const float* b1 = (const float*)d_in[2];
    const float* w2 = (const float*)d_in[3];
    const float* b2 = (const float*)d_in[4];
    float* out = (float*)d_out;
    int* idx = (int*)d_ws;   // 4096*8*4 B = 128 KiB scratch

    ca1d_score <<<BB, 256, 0, stream>>>(x, w1, b1, w2, b2, idx);
    ca1d_gather<<<BB, 256, 0, stream>>>(x, idx, out);
}

// Round 15
// 114.537 us; speedup vs baseline: 1.2364x; 1.0386x over previous
//
#include <hip/hip_runtime.h>
#include <math.h>

#define BB 4096
#define FF 64
#define RR 16   // F / RED
#define DD 512
#define KK 8

typedef float f32x4 __attribute__((ext_vector_type(4)));

// R9 structure — best measured (114.6 us). One block per batch, 256 threads,
// tiny LDS -> 8 blocks/CU; block-level stagger hides the MLP/gather tails.
// Ledger (R10-R14): every staging/pipelining/barrier-diet/split variant lost.
// All arithmetic BIT-FROZEN from the passing R8 kernel.
__global__ __launch_bounds__(256) void ca1d_fused(
    const float* __restrict__ x,   // [B,F,D]
    const float* __restrict__ w1,  // [R,F]
    const float* __restrict__ b1,  // [R]
    const float* __restrict__ w2,  // [F,R]
    const float* __restrict__ b2,  // [F]
    float* __restrict__ out)       // [B,K,D]
{
    __shared__ double s_pooled[FF];
    __shared__ double s_h[RR];
    __shared__ double s_z[FF];
    __shared__ float  s_w[FF];
    __shared__ int    s_idx[KK];

    const int b    = blockIdx.x;
    const int tid  = threadIdx.x;
    const int lane = tid & 63;
    const int wave = tid >> 6;   // 0..3

    const float* xb = x + (size_t)b * FF * DD;

    // ---- Stage 1 (BIT-FROZEN): pooled[f] = mean_D x[b,f,:].
    // Per-lane pair tree, xor-shuffle 32,16,8,4,2,1, *1/512 by lane 0.
    // unroll 4 -> 8 float4 loads + 4 independent shuffle chains in flight.
    #pragma unroll 4
    for (int f = wave; f < FF; f += 4) {
        const float4* row = reinterpret_cast<const float4*>(xb + f * DD);
        float4 v0 = row[lane];        // coalesced: 64 lanes x 16B
        float4 v1 = row[lane + 64];
        double s = ((double)v0.x + (double)v0.y) + ((double)v0.z + (double)v0.w)
                 + ((double)v1.x + (double)v1.y) + ((double)v1.z + (double)v1.w);
        #pragma unroll
        for (int off = 32; off > 0; off >>= 1)
            s += __shfl_xor(s, off, 64);
        if (lane == 0) s_pooled[f] = s * (1.0 / DD);
    }
    __syncthreads();

    // ---- Stage 2: h[r] = relu(dot(pooled, w1[r,:]) + b1[r])   (f64 exact, BIT-FROZEN)
    if (tid < RR) {
        double acc = (double)b1[tid];
        const float* wr = w1 + tid * FF;
        #pragma unroll
        for (int f = 0; f < FF; ++f) acc += s_pooled[f] * (double)wr[f];
        s_h[tid] = acc > 0.0 ? acc : 0.0;
    }
    __syncthreads();

    // ---- Stage 3: z[f] = dot(h, w2[f,:]) + b2[f]   (f64 exact, BIT-FROZEN)
    if (tid < FF) {
        double acc = (double)b2[tid];
        const float* wf = w2 + tid * RR;
        #pragma unroll
        for (int r = 0; r < RR; ++r) acc += s_h[r] * (double)wf[r];
        s_z[tid] = acc;
    }
    __syncthreads();

    // ---- Stage 4: top-K on the np-style THREE-ROUNDING sigmoid chain
    // (BIT-FROZEN):  e = f32(exp(-z)); den = f32(1+e); w = f32(1/den).
    // Rank-based selection == descending w, exact ties -> lower index.
    if (wave == 0) {
        float e   = (float)exp(-s_z[lane]);   // f64 exp -> f32 round
        float den = 1.0f + e;                 // f32 round
        float v   = 1.0f / den;               // f32 round
        s_w[lane] = v;
        int rank = 0;
        #pragma unroll
        for (int j = 0; j < FF; ++j) {
            float wj = s_w[j];                // uniform broadcast, conflict-free
            rank += (wj > v || (wj == v && j < lane)) ? 1 : 0;
        }
        if (rank < KK) s_idx[rank] = lane;
    }
    __syncthreads();

    // ---- Stage 5: gather 8 selected rows -> out[b, k, :]
    // nontemporal stores: out is never re-read; keep L2 for x rows.
    f32x4* ob = (f32x4*)(out + (size_t)b * KK * DD);
    #pragma unroll
    for (int i = tid; i < KK * DD / 4; i += 256) {   // 1024 float4, 4 per thread
        int k = i >> 7;        // / 128
        int c = i & 127;
        const f32x4* src = (const f32x4*)(xb + (size_t)s_idx[k] * DD);
        __builtin_nontemporal_store(src[c], ob + i);
    }
}

extern "C" void kernel_launch(void* const* d_in, const int* in_sizes, int n_in,
                              void* d_out, int out_size, void* d_ws, size_t ws_size,
                              hipStream_t stream) {
    const float* x  = (const float*)d_in[0];
    const float* w1 = (const float*)d_in[1];
    const float* b1 = (const float*)d_in[2];
    const float* w2 = (const float*)d_in[3];
    const float* b2 = (const float*)d_in[4];
    float* out = (float*)d_out;

    ca1d_fused<<<BB, 256, 0, stream>>>(x, w1, b1, w2, b2, out);
}

// Round 16
// 114.468 us; speedup vs baseline: 1.2371x; 1.0006x over previous
//
#include <hip/hip_runtime.h>
#include <math.h>

#define BB 4096
#define FF 64
#define RR 16   // F / RED
#define DD 512
#define KK 8

typedef float f32x4 __attribute__((ext_vector_type(4)));

// R9 structure (best measured, 114.5 us, reproduced twice within 0.05%)
// + __launch_bounds__(256, 8): force VGPR <= 64 so all 8 blocks/CU are
// actually resident (VGPR cliff: >64 VGPRs halves waves/SIMD). The MLP
// runs on wave 0 only, so any spill it takes is off the streaming path.
// All arithmetic BIT-FROZEN from the passing R8 kernel.
__global__ __launch_bounds__(256, 8) void ca1d_fused(
    const float* __restrict__ x,   // [B,F,D]
    const float* __restrict__ w1,  // [R,F]
    const float* __restrict__ b1,  // [R]
    const float* __restrict__ w2,  // [F,R]
    const float* __restrict__ b2,  // [F]
    float* __restrict__ out)       // [B,K,D]
{
    __shared__ double s_pooled[FF];
    __shared__ double s_h[RR];
    __shared__ double s_z[FF];
    __shared__ float  s_w[FF];
    __shared__ int    s_idx[KK];

    const int b    = blockIdx.x;
    const int tid  = threadIdx.x;
    const int lane = tid & 63;
    const int wave = tid >> 6;   // 0..3

    const float* xb = x + (size_t)b * FF * DD;

    // ---- Stage 1 (BIT-FROZEN): pooled[f] = mean_D x[b,f,:].
    // Per-lane pair tree, xor-shuffle 32,16,8,4,2,1, *1/512 by lane 0.
    // unroll 4 -> 8 float4 loads + 4 independent shuffle chains in flight.
    #pragma unroll 4
    for (int f = wave; f < FF; f += 4) {
        const float4* row = reinterpret_cast<const float4*>(xb + f * DD);
        float4 v0 = row[lane];        // coalesced: 64 lanes x 16B
        float4 v1 = row[lane + 64];
        double s = ((double)v0.x + (double)v0.y) + ((double)v0.z + (double)v0.w)
                 + ((double)v1.x + (double)v1.y) + ((double)v1.z + (double)v1.w);
        #pragma unroll
        for (int off = 32; off > 0; off >>= 1)
            s += __shfl_xor(s, off, 64);
        if (lane == 0) s_pooled[f] = s * (1.0 / DD);
    }
    __syncthreads();

    // ---- Stage 2: h[r] = relu(dot(pooled, w1[r,:]) + b1[r])   (f64 exact, BIT-FROZEN)
    if (tid < RR) {
        double acc = (double)b1[tid];
        const float* wr = w1 + tid * FF;
        #pragma unroll
        for (int f = 0; f < FF; ++f) acc += s_pooled[f] * (double)wr[f];
        s_h[tid] = acc > 0.0 ? acc : 0.0;
    }
    __syncthreads();

    // ---- Stage 3: z[f] = dot(h, w2[f,:]) + b2[f]   (f64 exact, BIT-FROZEN)
    if (tid < FF) {
        double acc = (double)b2[tid];
        const float* wf = w2 + tid * RR;
        #pragma unroll
        for (int r = 0; r < RR; ++r) acc += s_h[r] * (double)wf[r];
        s_z[tid] = acc;
    }
    __syncthreads();

    // ---- Stage 4: top-K on the np-style THREE-ROUNDING sigmoid chain
    // (BIT-FROZEN):  e = f32(exp(-z)); den = f32(1+e); w = f32(1/den).
    // Rank-based selection == descending w, exact ties -> lower index.
    if (wave == 0) {
        float e   = (float)exp(-s_z[lane]);   // f64 exp -> f32 round
        float den = 1.0f + e;                 // f32 round
        float v   = 1.0f / den;               // f32 round
        s_w[lane] = v;
        int rank = 0;
        #pragma unroll
        for (int j = 0; j < FF; ++j) {
            float wj = s_w[j];                // uniform broadcast, conflict-free
            rank += (wj > v || (wj == v && j < lane)) ? 1 : 0;
        }
        if (rank < KK) s_idx[rank] = lane;
    }
    __syncthreads();

    // ---- Stage 5: gather 8 selected rows -> out[b, k, :]
    // nontemporal stores: out is never re-read; keep L2 for x rows.
    f32x4* ob = (f32x4*)(out + (size_t)b * KK * DD);
    #pragma unroll
    for (int i = tid; i < KK * DD / 4; i += 256) {   // 1024 float4, 4 per thread
        int k = i >> 7;        // / 128
        int c = i & 127;
        const f32x4* src = (const f32x4*)(xb + (size_t)s_idx[k] * DD);
        __builtin_nontemporal_store(src[c], ob + i);
    }
}

extern "C" void kernel_launch(void* const* d_in, const int* in_sizes, int n_in,
                              void* d_out, int out_size, void* d_ws, size_t ws_size,
                              hipStream_t stream) {
    const float* x  = (const float*)d_in[0];
    const float* w1 = (const float*)d_in[1];
    const float* b1 = (const float*)d_in[2];
    const float* w2 = (const float*)d_in[3];
    const float* b2 = (const float*)d_in[4];
    float* out = (float*)d_out;

    ca1d_fused<<<BB, 256, 0, stream>>>(x, w1, b1, w2, b2, out);
}